// Round 6
// baseline (84.165 us; speedup 1.0000x reference)
//
#include <hip/hip_runtime.h>

// TweetRep: x (8,6,32,32,30) int32, embeddings (50000,64) f32 -> out (8,384,32,32) f32.
// 4 pixels per wave (16-lane groups, lane = 4 dims as float4).
// Round-6: identical math to round 5 (two-gather + chunked online softmax),
// but forced under the 64-VGPR occupancy cliff: rolled chunk loops with
// unroll(1) (stops load-hoisting that pushed r5 to VGPR=72 / 4 waves/SIMD)
// + __launch_bounds__(256,8) (VGPR cap 64 -> 8 waves/SIMD). r2-r5 all sat
// latency-bound at 4 waves/SIMD: dur ~44-47us, VALUBusy ~40%, Occ 24%.

#define LTOK 30
#define NPIX (8 * 6 * 32 * 32)   // 49152
#define L2E  1.4426950408889634f

template <int CTRL>
__device__ __forceinline__ float dppadd(float v) {
    // v += dpp_permute(v); folds to v_add_f32 dpp, bound_ctrl -> 0
    int t = __builtin_amdgcn_update_dpp(0, __float_as_int(v), CTRL, 0xF, 0xF, true);
    return v + __int_as_float(t);
}

// sum across the 16-lane group (butterfly: xor1, xor2, mirror8, mirror16)
__device__ __forceinline__ float group16_sum(float p) {
    p = dppadd<0xB1>(p);    // quad_perm {1,0,3,2}
    p = dppadd<0x4E>(p);    // quad_perm {2,3,0,1}
    p = dppadd<0x141>(p);   // row_half_mirror
    p = dppadd<0x140>(p);   // row_mirror
    return p;
}

__device__ __forceinline__ float dot4_group(const float4& w, const float4& V) {
    float p = w.x * V.x;
    p = fmaf(w.y, V.y, p);
    p = fmaf(w.z, V.z, p);
    p = fmaf(w.w, V.w, p);
    return group16_sum(p);
}

__global__ __launch_bounds__(256, 8) void tweetrep_kernel(
        const int* __restrict__ x, const float* __restrict__ emb,
        float* __restrict__ out)
{
    const int lane16 = threadIdx.x & 15;
    const int pix    = (blockIdx.x << 4) | (threadIdx.x >> 4);  // 16 pixels/block
    const int eoff   = lane16 << 2;                             // this lane's 4 dims
    const int*   xp   = x + pix * LTOK;
    const float* embl = emb + eoff;

    // ---- pass A: V = sum of the 30 rows (only V stays live) ----
    float4 V = make_float4(0.f, 0.f, 0.f, 0.f);
#pragma unroll 1
    for (int c = 0; c < 28; c += 4) {
        int4 ii = *reinterpret_cast<const int4*>(xp + c);
        float4 w0 = *reinterpret_cast<const float4*>(embl + ((size_t)ii.x << 6));
        float4 w1 = *reinterpret_cast<const float4*>(embl + ((size_t)ii.y << 6));
        float4 w2 = *reinterpret_cast<const float4*>(embl + ((size_t)ii.z << 6));
        float4 w3 = *reinterpret_cast<const float4*>(embl + ((size_t)ii.w << 6));
        V.x += (w0.x + w1.x) + (w2.x + w3.x);
        V.y += (w0.y + w1.y) + (w2.y + w3.y);
        V.z += (w0.z + w1.z) + (w2.z + w3.z);
        V.w += (w0.w + w1.w) + (w2.w + w3.w);
    }
    {
        int2 ii = *reinterpret_cast<const int2*>(xp + 28);
        float4 w0 = *reinterpret_cast<const float4*>(embl + ((size_t)ii.x << 6));
        float4 w1 = *reinterpret_cast<const float4*>(embl + ((size_t)ii.y << 6));
        V.x += w0.x + w1.x; V.y += w0.y + w1.y;
        V.z += w0.z + w1.z; V.w += w0.w + w1.w;
    }

    // ---- pass B: re-gather, chunk-of-4 online softmax (rolled) ----
    float4 acc = make_float4(0.f, 0.f, 0.f, 0.f);
    float  den = 0.f;
    float  m   = -3.0e38f;
#pragma unroll 1
    for (int c = 0; c < 28; c += 4) {
        int4 ii = *reinterpret_cast<const int4*>(xp + c);
        float4 w0 = *reinterpret_cast<const float4*>(embl + ((size_t)ii.x << 6));
        float4 w1 = *reinterpret_cast<const float4*>(embl + ((size_t)ii.y << 6));
        float4 w2 = *reinterpret_cast<const float4*>(embl + ((size_t)ii.z << 6));
        float4 w3 = *reinterpret_cast<const float4*>(embl + ((size_t)ii.w << 6));
        float p0 = dot4_group(w0, V);
        float p1 = dot4_group(w1, V);
        float p2 = dot4_group(w2, V);
        float p3 = dot4_group(w3, V);

        const float pm = fmaxf(fmaxf(p0, p1), fmaxf(p2, p3));
        const float mn = fmaxf(m, pm);
        const float sc = __builtin_exp2f((m - mn) * L2E);   // 0 on first chunk
        m = mn;
        const float e0 = __builtin_exp2f((p0 - mn) * L2E);
        const float e1 = __builtin_exp2f((p1 - mn) * L2E);
        const float e2 = __builtin_exp2f((p2 - mn) * L2E);
        const float e3 = __builtin_exp2f((p3 - mn) * L2E);
        acc.x = fmaf(acc.x, sc, 0.f); acc.y = fmaf(acc.y, sc, 0.f);
        acc.z = fmaf(acc.z, sc, 0.f); acc.w = fmaf(acc.w, sc, 0.f);
        den  *= sc;
        acc.x = fmaf(e0, w0.x, acc.x); acc.y = fmaf(e0, w0.y, acc.y);
        acc.z = fmaf(e0, w0.z, acc.z); acc.w = fmaf(e0, w0.w, acc.w);
        acc.x = fmaf(e1, w1.x, acc.x); acc.y = fmaf(e1, w1.y, acc.y);
        acc.z = fmaf(e1, w1.z, acc.z); acc.w = fmaf(e1, w1.w, acc.w);
        acc.x = fmaf(e2, w2.x, acc.x); acc.y = fmaf(e2, w2.y, acc.y);
        acc.z = fmaf(e2, w2.z, acc.z); acc.w = fmaf(e2, w2.w, acc.w);
        acc.x = fmaf(e3, w3.x, acc.x); acc.y = fmaf(e3, w3.y, acc.y);
        acc.z = fmaf(e3, w3.z, acc.z); acc.w = fmaf(e3, w3.w, acc.w);
        den += (e0 + e1) + (e2 + e3);
    }
    {
        int2 ii = *reinterpret_cast<const int2*>(xp + 28);
        float4 w0 = *reinterpret_cast<const float4*>(embl + ((size_t)ii.x << 6));
        float4 w1 = *reinterpret_cast<const float4*>(embl + ((size_t)ii.y << 6));
        float p0 = dot4_group(w0, V);
        float p1 = dot4_group(w1, V);
        const float pm = fmaxf(p0, p1);
        const float mn = fmaxf(m, pm);
        const float sc = __builtin_exp2f((m - mn) * L2E);
        const float e0 = __builtin_exp2f((p0 - mn) * L2E);
        const float e1 = __builtin_exp2f((p1 - mn) * L2E);
        acc.x *= sc; acc.y *= sc; acc.z *= sc; acc.w *= sc; den *= sc;
        acc.x = fmaf(e0, w0.x, acc.x); acc.y = fmaf(e0, w0.y, acc.y);
        acc.z = fmaf(e0, w0.z, acc.z); acc.w = fmaf(e0, w0.w, acc.w);
        acc.x = fmaf(e1, w1.x, acc.x); acc.y = fmaf(e1, w1.y, acc.y);
        acc.z = fmaf(e1, w1.z, acc.z); acc.w = fmaf(e1, w1.w, acc.w);
        den += e0 + e1;
    }
    const float inv = __builtin_amdgcn_rcpf(den);

    // ---- out[bt*64 + e][hw], e = 4*lane16 + j ----
    const int bt = pix >> 10, hw = pix & 1023;
    float* op = out + (((size_t)(bt * 64 + eoff)) << 10) + hw;
    op[0]    = acc.x * inv;
    op[1024] = acc.y * inv;
    op[2048] = acc.z * inv;
    op[3072] = acc.w * inv;
}

extern "C" void kernel_launch(void* const* d_in, const int* in_sizes, int n_in,
                              void* d_out, int out_size, void* d_ws, size_t ws_size,
                              hipStream_t stream)
{
    const int*   x   = (const int*)d_in[0];
    const float* emb = (const float*)d_in[1];
    float*       out = (float*)d_out;

    const int blocks = NPIX / 16;   // 16 pixels per 256-thread block
    tweetrep_kernel<<<blocks, 256, 0, stream>>>(x, emb, out);
}

// Round 7
// 40.311 us; speedup vs baseline: 2.0879x; 2.0879x over previous
//
#include <hip/hip_runtime.h>

// TweetRep: x (8,6,32,32,30) int32, embeddings (50000,64) f32 -> out (8,384,32,32) f32.
// Round-7: rounds 2-6 all pinned at (FETCH+WRITE)/dur ~= 3.5 TB/s regardless of
// occupancy (24%..69%) -> L2-miss-fill-bound on the random gather (12.8MB f32
// table >> 4MiB/XCD L2). Lever = missed BYTES: convert table to fp16 in d_ws
// (6.4MB) once per call, gather fp16 rows (128B/row), do ALL math in f32 via
// v_fma_mix (fmaf((float)h, f, f)). Same two-pass chunked online softmax as r5.

#define LTOK 30
#define NPIX (8 * 6 * 32 * 32)   // 49152
#define L2E  1.4426950408889634f
#define TABROWS 50000
#define TABN (TABROWS * 64)      // 3.2M floats

typedef _Float16 h2 __attribute__((ext_vector_type(2)));

template <int CTRL>
__device__ __forceinline__ float dppadd(float v) {
    int t = __builtin_amdgcn_update_dpp(0, __float_as_int(v), CTRL, 0xF, 0xF, true);
    return v + __int_as_float(t);
}

// sum across the 16-lane group (butterfly: xor1, xor2, mirror8, mirror16)
__device__ __forceinline__ float group16_sum(float p) {
    p = dppadd<0xB1>(p);    // quad_perm {1,0,3,2}
    p = dppadd<0x4E>(p);    // quad_perm {2,3,0,1}
    p = dppadd<0x141>(p);   // row_half_mirror
    p = dppadd<0x140>(p);   // row_mirror
    return p;
}

__device__ __forceinline__ h2 u2h(unsigned int u) {
    return __builtin_bit_cast(h2, u);
}

// ---- prep: f32 table -> fp16 table (RN) in workspace ----
__global__ __launch_bounds__(256) void cvt_kernel(
        const float4* __restrict__ in, uint2* __restrict__ out)
{
    const int i = blockIdx.x * 256 + threadIdx.x;   // 800000 threads exactly
    float4 f = in[i];
    h2 a = { (_Float16)f.x, (_Float16)f.y };
    h2 b = { (_Float16)f.z, (_Float16)f.w };
    out[i] = make_uint2(__builtin_bit_cast(unsigned int, a),
                        __builtin_bit_cast(unsigned int, b));
}

// ---- main: fp16-table gather, f32 math ----
__global__ __launch_bounds__(256) void tweetrep_f16(
        const int* __restrict__ x, const uint2* __restrict__ tab,
        float* __restrict__ out)
{
    const int lane16 = threadIdx.x & 15;
    const int pix    = (blockIdx.x << 4) | (threadIdx.x >> 4);  // 16 pixels/block
    const int*   xp  = x + pix * LTOK;
    // row = 64 halves = 16 uint2; this lane's 4 dims = uint2 #lane16 of the row
    const uint2* tpl = tab + lane16;

    float one = 1.0f;
    asm volatile("" : "+v"(one));   // keep fmaf(h,one,V) as v_fma_mix (no fold)

    // ---- pass A: V = sum of the 30 rows ----
    float4 V = make_float4(0.f, 0.f, 0.f, 0.f);
#pragma unroll
    for (int c = 0; c < 28; c += 4) {
        int4 ii = *reinterpret_cast<const int4*>(xp + c);
        uint2 u0 = tpl[(size_t)ii.x << 4];
        uint2 u1 = tpl[(size_t)ii.y << 4];
        uint2 u2 = tpl[(size_t)ii.z << 4];
        uint2 u3 = tpl[(size_t)ii.w << 4];
        h2 a0 = u2h(u0.x), b0 = u2h(u0.y), a1 = u2h(u1.x), b1 = u2h(u1.y);
        h2 a2 = u2h(u2.x), b2 = u2h(u2.y), a3 = u2h(u3.x), b3 = u2h(u3.y);
        V.x = fmaf((float)a0.x, one, V.x); V.y = fmaf((float)a0.y, one, V.y);
        V.z = fmaf((float)b0.x, one, V.z); V.w = fmaf((float)b0.y, one, V.w);
        V.x = fmaf((float)a1.x, one, V.x); V.y = fmaf((float)a1.y, one, V.y);
        V.z = fmaf((float)b1.x, one, V.z); V.w = fmaf((float)b1.y, one, V.w);
        V.x = fmaf((float)a2.x, one, V.x); V.y = fmaf((float)a2.y, one, V.y);
        V.z = fmaf((float)b2.x, one, V.z); V.w = fmaf((float)b2.y, one, V.w);
        V.x = fmaf((float)a3.x, one, V.x); V.y = fmaf((float)a3.y, one, V.y);
        V.z = fmaf((float)b3.x, one, V.z); V.w = fmaf((float)b3.y, one, V.w);
    }
    {
        int2 ii = *reinterpret_cast<const int2*>(xp + 28);
        uint2 u0 = tpl[(size_t)ii.x << 4];
        uint2 u1 = tpl[(size_t)ii.y << 4];
        h2 a0 = u2h(u0.x), b0 = u2h(u0.y), a1 = u2h(u1.x), b1 = u2h(u1.y);
        V.x = fmaf((float)a0.x, one, V.x); V.y = fmaf((float)a0.y, one, V.y);
        V.z = fmaf((float)b0.x, one, V.z); V.w = fmaf((float)b0.y, one, V.w);
        V.x = fmaf((float)a1.x, one, V.x); V.y = fmaf((float)a1.y, one, V.y);
        V.z = fmaf((float)b1.x, one, V.z); V.w = fmaf((float)b1.y, one, V.w);
    }

    // ---- pass B: re-gather, chunk-of-4 online softmax ----
    float4 acc = make_float4(0.f, 0.f, 0.f, 0.f);
    float  den = 0.f;
    float  m   = -3.0e38f;
#pragma unroll
    for (int c = 0; c < 28; c += 4) {
        int4 ii = *reinterpret_cast<const int4*>(xp + c);
        uint2 u0 = tpl[(size_t)ii.x << 4];
        uint2 u1 = tpl[(size_t)ii.y << 4];
        uint2 u2 = tpl[(size_t)ii.z << 4];
        uint2 u3 = tpl[(size_t)ii.w << 4];
        h2 a0 = u2h(u0.x), b0 = u2h(u0.y), a1 = u2h(u1.x), b1 = u2h(u1.y);
        h2 a2 = u2h(u2.x), b2 = u2h(u2.y), a3 = u2h(u3.x), b3 = u2h(u3.y);

        float p0 = fmaf((float)a0.x, V.x, fmaf((float)a0.y, V.y,
                   fmaf((float)b0.x, V.z, (float)b0.y * V.w)));
        float p1 = fmaf((float)a1.x, V.x, fmaf((float)a1.y, V.y,
                   fmaf((float)b1.x, V.z, (float)b1.y * V.w)));
        float p2 = fmaf((float)a2.x, V.x, fmaf((float)a2.y, V.y,
                   fmaf((float)b2.x, V.z, (float)b2.y * V.w)));
        float p3 = fmaf((float)a3.x, V.x, fmaf((float)a3.y, V.y,
                   fmaf((float)b3.x, V.z, (float)b3.y * V.w)));
        p0 = group16_sum(p0);
        p1 = group16_sum(p1);
        p2 = group16_sum(p2);
        p3 = group16_sum(p3);

        const float pm = fmaxf(fmaxf(p0, p1), fmaxf(p2, p3));
        const float mn = fmaxf(m, pm);
        const float sc = __builtin_exp2f((m - mn) * L2E);   // 0 on first chunk
        m = mn;
        const float e0 = __builtin_exp2f((p0 - mn) * L2E);
        const float e1 = __builtin_exp2f((p1 - mn) * L2E);
        const float e2 = __builtin_exp2f((p2 - mn) * L2E);
        const float e3 = __builtin_exp2f((p3 - mn) * L2E);
        acc.x *= sc; acc.y *= sc; acc.z *= sc; acc.w *= sc; den *= sc;
        acc.x = fmaf((float)a0.x, e0, acc.x); acc.y = fmaf((float)a0.y, e0, acc.y);
        acc.z = fmaf((float)b0.x, e0, acc.z); acc.w = fmaf((float)b0.y, e0, acc.w);
        acc.x = fmaf((float)a1.x, e1, acc.x); acc.y = fmaf((float)a1.y, e1, acc.y);
        acc.z = fmaf((float)b1.x, e1, acc.z); acc.w = fmaf((float)b1.y, e1, acc.w);
        acc.x = fmaf((float)a2.x, e2, acc.x); acc.y = fmaf((float)a2.y, e2, acc.y);
        acc.z = fmaf((float)b2.x, e2, acc.z); acc.w = fmaf((float)b2.y, e2, acc.w);
        acc.x = fmaf((float)a3.x, e3, acc.x); acc.y = fmaf((float)a3.y, e3, acc.y);
        acc.z = fmaf((float)b3.x, e3, acc.z); acc.w = fmaf((float)b3.y, e3, acc.w);
        den += (e0 + e1) + (e2 + e3);
    }
    {
        int2 ii = *reinterpret_cast<const int2*>(xp + 28);
        uint2 u0 = tpl[(size_t)ii.x << 4];
        uint2 u1 = tpl[(size_t)ii.y << 4];
        h2 a0 = u2h(u0.x), b0 = u2h(u0.y), a1 = u2h(u1.x), b1 = u2h(u1.y);
        float p0 = fmaf((float)a0.x, V.x, fmaf((float)a0.y, V.y,
                   fmaf((float)b0.x, V.z, (float)b0.y * V.w)));
        float p1 = fmaf((float)a1.x, V.x, fmaf((float)a1.y, V.y,
                   fmaf((float)b1.x, V.z, (float)b1.y * V.w)));
        p0 = group16_sum(p0);
        p1 = group16_sum(p1);
        const float pm = fmaxf(p0, p1);
        const float mn = fmaxf(m, pm);
        const float sc = __builtin_exp2f((m - mn) * L2E);
        const float e0 = __builtin_exp2f((p0 - mn) * L2E);
        const float e1 = __builtin_exp2f((p1 - mn) * L2E);
        acc.x *= sc; acc.y *= sc; acc.z *= sc; acc.w *= sc; den *= sc;
        acc.x = fmaf((float)a0.x, e0, acc.x); acc.y = fmaf((float)a0.y, e0, acc.y);
        acc.z = fmaf((float)b0.x, e0, acc.z); acc.w = fmaf((float)b0.y, e0, acc.w);
        acc.x = fmaf((float)a1.x, e1, acc.x); acc.y = fmaf((float)a1.y, e1, acc.y);
        acc.z = fmaf((float)b1.x, e1, acc.z); acc.w = fmaf((float)b1.y, e1, acc.w);
        den += e0 + e1;
    }
    const float inv = __builtin_amdgcn_rcpf(den);

    // ---- out[bt*64 + e][hw], e = 4*lane16 + j ----
    const int bt = pix >> 10, hw = pix & 1023;
    float* op = out + (((size_t)(bt * 64 + (lane16 << 2))) << 10) + hw;
    op[0]    = acc.x * inv;
    op[1024] = acc.y * inv;
    op[2048] = acc.z * inv;
    op[3072] = acc.w * inv;
}

// ---- f32 fallback (round-5 kernel) if workspace is too small ----
__device__ __forceinline__ float dot4_group(const float4& w, const float4& V) {
    float p = w.x * V.x;
    p = fmaf(w.y, V.y, p);
    p = fmaf(w.z, V.z, p);
    p = fmaf(w.w, V.w, p);
    return group16_sum(p);
}

__global__ __launch_bounds__(256) void tweetrep_f32(
        const int* __restrict__ x, const float* __restrict__ emb,
        float* __restrict__ out)
{
    const int lane16 = threadIdx.x & 15;
    const int pix    = (blockIdx.x << 4) | (threadIdx.x >> 4);
    const int eoff   = lane16 << 2;
    const int*   xp   = x + pix * LTOK;
    const float* embl = emb + eoff;

    float4 V = make_float4(0.f, 0.f, 0.f, 0.f);
#pragma unroll
    for (int c = 0; c < 28; c += 4) {
        int4 ii = *reinterpret_cast<const int4*>(xp + c);
        float4 w0 = *reinterpret_cast<const float4*>(embl + ((size_t)ii.x << 6));
        float4 w1 = *reinterpret_cast<const float4*>(embl + ((size_t)ii.y << 6));
        float4 w2 = *reinterpret_cast<const float4*>(embl + ((size_t)ii.z << 6));
        float4 w3 = *reinterpret_cast<const float4*>(embl + ((size_t)ii.w << 6));
        V.x += (w0.x + w1.x) + (w2.x + w3.x);
        V.y += (w0.y + w1.y) + (w2.y + w3.y);
        V.z += (w0.z + w1.z) + (w2.z + w3.z);
        V.w += (w0.w + w1.w) + (w2.w + w3.w);
    }
    {
        int2 ii = *reinterpret_cast<const int2*>(xp + 28);
        float4 w0 = *reinterpret_cast<const float4*>(embl + ((size_t)ii.x << 6));
        float4 w1 = *reinterpret_cast<const float4*>(embl + ((size_t)ii.y << 6));
        V.x += w0.x + w1.x; V.y += w0.y + w1.y;
        V.z += w0.z + w1.z; V.w += w0.w + w1.w;
    }

    float4 acc = make_float4(0.f, 0.f, 0.f, 0.f);
    float  den = 0.f;
    float  m   = -3.0e38f;
#pragma unroll
    for (int c = 0; c < 28; c += 4) {
        int4 ii = *reinterpret_cast<const int4*>(xp + c);
        float4 w0 = *reinterpret_cast<const float4*>(embl + ((size_t)ii.x << 6));
        float4 w1 = *reinterpret_cast<const float4*>(embl + ((size_t)ii.y << 6));
        float4 w2 = *reinterpret_cast<const float4*>(embl + ((size_t)ii.z << 6));
        float4 w3 = *reinterpret_cast<const float4*>(embl + ((size_t)ii.w << 6));
        float p0 = dot4_group(w0, V);
        float p1 = dot4_group(w1, V);
        float p2 = dot4_group(w2, V);
        float p3 = dot4_group(w3, V);
        const float pm = fmaxf(fmaxf(p0, p1), fmaxf(p2, p3));
        const float mn = fmaxf(m, pm);
        const float sc = __builtin_exp2f((m - mn) * L2E);
        m = mn;
        const float e0 = __builtin_exp2f((p0 - mn) * L2E);
        const float e1 = __builtin_exp2f((p1 - mn) * L2E);
        const float e2 = __builtin_exp2f((p2 - mn) * L2E);
        const float e3 = __builtin_exp2f((p3 - mn) * L2E);
        acc.x *= sc; acc.y *= sc; acc.z *= sc; acc.w *= sc; den *= sc;
        acc.x = fmaf(e0, w0.x, acc.x); acc.y = fmaf(e0, w0.y, acc.y);
        acc.z = fmaf(e0, w0.z, acc.z); acc.w = fmaf(e0, w0.w, acc.w);
        acc.x = fmaf(e1, w1.x, acc.x); acc.y = fmaf(e1, w1.y, acc.y);
        acc.z = fmaf(e1, w1.z, acc.z); acc.w = fmaf(e1, w1.w, acc.w);
        acc.x = fmaf(e2, w2.x, acc.x); acc.y = fmaf(e2, w2.y, acc.y);
        acc.z = fmaf(e2, w2.z, acc.z); acc.w = fmaf(e2, w2.w, acc.w);
        acc.x = fmaf(e3, w3.x, acc.x); acc.y = fmaf(e3, w3.y, acc.y);
        acc.z = fmaf(e3, w3.z, acc.z); acc.w = fmaf(e3, w3.w, acc.w);
        den += (e0 + e1) + (e2 + e3);
    }
    {
        int2 ii = *reinterpret_cast<const int2*>(xp + 28);
        float4 w0 = *reinterpret_cast<const float4*>(embl + ((size_t)ii.x << 6));
        float4 w1 = *reinterpret_cast<const float4*>(embl + ((size_t)ii.y << 6));
        float p0 = dot4_group(w0, V);
        float p1 = dot4_group(w1, V);
        const float pm = fmaxf(p0, p1);
        const float mn = fmaxf(m, pm);
        const float sc = __builtin_exp2f((m - mn) * L2E);
        const float e0 = __builtin_exp2f((p0 - mn) * L2E);
        const float e1 = __builtin_exp2f((p1 - mn) * L2E);
        acc.x *= sc; acc.y *= sc; acc.z *= sc; acc.w *= sc; den *= sc;
        acc.x = fmaf(e0, w0.x, acc.x); acc.y = fmaf(e0, w0.y, acc.y);
        acc.z = fmaf(e0, w0.z, acc.z); acc.w = fmaf(e0, w0.w, acc.w);
        acc.x = fmaf(e1, w1.x, acc.x); acc.y = fmaf(e1, w1.y, acc.y);
        acc.z = fmaf(e1, w1.z, acc.z); acc.w = fmaf(e1, w1.w, acc.w);
        den += e0 + e1;
    }
    const float inv = __builtin_amdgcn_rcpf(den);

    const int bt = pix >> 10, hw = pix & 1023;
    float* op = out + (((size_t)(bt * 64 + eoff)) << 10) + hw;
    op[0]    = acc.x * inv;
    op[1024] = acc.y * inv;
    op[2048] = acc.z * inv;
    op[3072] = acc.w * inv;
}

extern "C" void kernel_launch(void* const* d_in, const int* in_sizes, int n_in,
                              void* d_out, int out_size, void* d_ws, size_t ws_size,
                              hipStream_t stream)
{
    const int*   x   = (const int*)d_in[0];
    const float* emb = (const float*)d_in[1];
    float*       out = (float*)d_out;

    const size_t need = (size_t)TABN * 2;   // 6.4 MB fp16 table
    if (ws_size >= need) {
        cvt_kernel<<<TABN / 4 / 256, 256, 0, stream>>>(
            (const float4*)emb, (uint2*)d_ws);
        tweetrep_f16<<<NPIX / 16, 256, 0, stream>>>(
            x, (const uint2*)d_ws, out);
    } else {
        tweetrep_f32<<<NPIX / 16, 256, 0, stream>>>(x, emb, out);
    }
}

// Round 8
// 38.153 us; speedup vs baseline: 2.2060x; 1.0566x over previous
//
#include <hip/hip_runtime.h>

// TweetRep: x (8,6,32,32,30) int32, embeddings (50000,64) f32 -> out (8,384,32,32) f32.
// Round-8: SINGLE-gather fp16 kernel. r7 halved bytes/row but still gathered
// every row twice (pass A for V, pass B for softmax) because 30 f32 slices =
// 120 VGPR didn't fit. In fp16 a row slice is uint2 = 2 VGPR -> all 30 rows
// live in 60 registers: gather once, accumulate V in-flight, then run the
// chunked online softmax entirely from registers (v_fma_mix reads fp16 from
// reg halves for free). Gather stream halves: 2.95M -> 1.47M row requests.

#define LTOK 30
#define NPIX (8 * 6 * 32 * 32)   // 49152
#define L2E  1.4426950408889634f
#define TABROWS 50000
#define TABN (TABROWS * 64)      // 3.2M floats

typedef _Float16 h2 __attribute__((ext_vector_type(2)));

template <int CTRL>
__device__ __forceinline__ float dppadd(float v) {
    int t = __builtin_amdgcn_update_dpp(0, __float_as_int(v), CTRL, 0xF, 0xF, true);
    return v + __int_as_float(t);
}

// sum across the 16-lane group (butterfly: xor1, xor2, mirror8, mirror16)
__device__ __forceinline__ float group16_sum(float p) {
    p = dppadd<0xB1>(p);    // quad_perm {1,0,3,2}
    p = dppadd<0x4E>(p);    // quad_perm {2,3,0,1}
    p = dppadd<0x141>(p);   // row_half_mirror
    p = dppadd<0x140>(p);   // row_mirror
    return p;
}

__device__ __forceinline__ h2 u2h(unsigned int u) {
    return __builtin_bit_cast(h2, u);
}

// ---- prep: f32 table -> fp16 table (RN) in workspace ----
__global__ __launch_bounds__(256) void cvt_kernel(
        const float4* __restrict__ in, uint2* __restrict__ out)
{
    const int i = blockIdx.x * 256 + threadIdx.x;   // 800000 threads exactly
    float4 f = in[i];
    h2 a = { (_Float16)f.x, (_Float16)f.y };
    h2 b = { (_Float16)f.z, (_Float16)f.w };
    out[i] = make_uint2(__builtin_bit_cast(unsigned int, a),
                        __builtin_bit_cast(unsigned int, b));
}

// ---- main: single fp16 gather, rows live in VGPRs, f32 math ----
__global__ __launch_bounds__(256) void tweetrep_f16(
        const int* __restrict__ x, const uint2* __restrict__ tab,
        float* __restrict__ out)
{
    const int lane16 = threadIdx.x & 15;
    const int pix    = (blockIdx.x << 4) | (threadIdx.x >> 4);  // 16 pixels/block
    const int*   xp  = x + pix * LTOK;
    // row = 64 halves = 16 uint2; this lane's 4 dims = uint2 #lane16 of the row
    const uint2* tpl = tab + lane16;

    float one = 1.0f;
    asm volatile("" : "+v"(one));   // keep fmaf((float)h, one, V) as v_fma_mix

    // ---- single gather: all 30 row-slices into registers ----
    uint2 wg[LTOK];
#pragma unroll
    for (int c = 0; c < 28; c += 4) {
        int4 ii = *reinterpret_cast<const int4*>(xp + c);
        wg[c]     = tpl[(size_t)ii.x << 4];
        wg[c + 1] = tpl[(size_t)ii.y << 4];
        wg[c + 2] = tpl[(size_t)ii.z << 4];
        wg[c + 3] = tpl[(size_t)ii.w << 4];
    }
    {
        int2 ii = *reinterpret_cast<const int2*>(xp + 28);
        wg[28] = tpl[(size_t)ii.x << 4];
        wg[29] = tpl[(size_t)ii.y << 4];
    }

    // ---- V = sum of rows (f32 accum via v_fma_mix) ----
    float4 V = make_float4(0.f, 0.f, 0.f, 0.f);
#pragma unroll
    for (int l = 0; l < LTOK; ++l) {
        h2 a = u2h(wg[l].x), b = u2h(wg[l].y);
        V.x = fmaf((float)a.x, one, V.x); V.y = fmaf((float)a.y, one, V.y);
        V.z = fmaf((float)b.x, one, V.z); V.w = fmaf((float)b.y, one, V.w);
    }

    // ---- chunk-of-4 online softmax, consuming wg from registers ----
    float4 acc = make_float4(0.f, 0.f, 0.f, 0.f);
    float  den = 0.f;
    float  m   = -3.0e38f;
#pragma unroll
    for (int c = 0; c < 28; c += 4) {
        h2 a0 = u2h(wg[c].x),     b0 = u2h(wg[c].y);
        h2 a1 = u2h(wg[c + 1].x), b1 = u2h(wg[c + 1].y);
        h2 a2 = u2h(wg[c + 2].x), b2 = u2h(wg[c + 2].y);
        h2 a3 = u2h(wg[c + 3].x), b3 = u2h(wg[c + 3].y);

        float p0 = fmaf((float)a0.x, V.x, fmaf((float)a0.y, V.y,
                   fmaf((float)b0.x, V.z, (float)b0.y * V.w)));
        float p1 = fmaf((float)a1.x, V.x, fmaf((float)a1.y, V.y,
                   fmaf((float)b1.x, V.z, (float)b1.y * V.w)));
        float p2 = fmaf((float)a2.x, V.x, fmaf((float)a2.y, V.y,
                   fmaf((float)b2.x, V.z, (float)b2.y * V.w)));
        float p3 = fmaf((float)a3.x, V.x, fmaf((float)a3.y, V.y,
                   fmaf((float)b3.x, V.z, (float)b3.y * V.w)));
        p0 = group16_sum(p0);
        p1 = group16_sum(p1);
        p2 = group16_sum(p2);
        p3 = group16_sum(p3);

        const float pm = fmaxf(fmaxf(p0, p1), fmaxf(p2, p3));
        const float mn = fmaxf(m, pm);
        const float sc = __builtin_exp2f((m - mn) * L2E);   // 0 on first chunk
        m = mn;
        const float e0 = __builtin_exp2f((p0 - mn) * L2E);
        const float e1 = __builtin_exp2f((p1 - mn) * L2E);
        const float e2 = __builtin_exp2f((p2 - mn) * L2E);
        const float e3 = __builtin_exp2f((p3 - mn) * L2E);
        acc.x *= sc; acc.y *= sc; acc.z *= sc; acc.w *= sc; den *= sc;
        acc.x = fmaf((float)a0.x, e0, acc.x); acc.y = fmaf((float)a0.y, e0, acc.y);
        acc.z = fmaf((float)b0.x, e0, acc.z); acc.w = fmaf((float)b0.y, e0, acc.w);
        acc.x = fmaf((float)a1.x, e1, acc.x); acc.y = fmaf((float)a1.y, e1, acc.y);
        acc.z = fmaf((float)b1.x, e1, acc.z); acc.w = fmaf((float)b1.y, e1, acc.w);
        acc.x = fmaf((float)a2.x, e2, acc.x); acc.y = fmaf((float)a2.y, e2, acc.y);
        acc.z = fmaf((float)b2.x, e2, acc.z); acc.w = fmaf((float)b2.y, e2, acc.w);
        acc.x = fmaf((float)a3.x, e3, acc.x); acc.y = fmaf((float)a3.y, e3, acc.y);
        acc.z = fmaf((float)b3.x, e3, acc.z); acc.w = fmaf((float)b3.y, e3, acc.w);
        den += (e0 + e1) + (e2 + e3);
    }
    {
        h2 a0 = u2h(wg[28].x), b0 = u2h(wg[28].y);
        h2 a1 = u2h(wg[29].x), b1 = u2h(wg[29].y);
        float p0 = fmaf((float)a0.x, V.x, fmaf((float)a0.y, V.y,
                   fmaf((float)b0.x, V.z, (float)b0.y * V.w)));
        float p1 = fmaf((float)a1.x, V.x, fmaf((float)a1.y, V.y,
                   fmaf((float)b1.x, V.z, (float)b1.y * V.w)));
        p0 = group16_sum(p0);
        p1 = group16_sum(p1);
        const float pm = fmaxf(p0, p1);
        const float mn = fmaxf(m, pm);
        const float sc = __builtin_exp2f((m - mn) * L2E);
        const float e0 = __builtin_exp2f((p0 - mn) * L2E);
        const float e1 = __builtin_exp2f((p1 - mn) * L2E);
        acc.x *= sc; acc.y *= sc; acc.z *= sc; acc.w *= sc; den *= sc;
        acc.x = fmaf((float)a0.x, e0, acc.x); acc.y = fmaf((float)a0.y, e0, acc.y);
        acc.z = fmaf((float)b0.x, e0, acc.z); acc.w = fmaf((float)b0.y, e0, acc.w);
        acc.x = fmaf((float)a1.x, e1, acc.x); acc.y = fmaf((float)a1.y, e1, acc.y);
        acc.z = fmaf((float)b1.x, e1, acc.z); acc.w = fmaf((float)b1.y, e1, acc.w);
        den += e0 + e1;
    }
    const float inv = __builtin_amdgcn_rcpf(den);

    // ---- out[bt*64 + e][hw], e = 4*lane16 + j ----
    const int bt = pix >> 10, hw = pix & 1023;
    float* op = out + (((size_t)(bt * 64 + (lane16 << 2))) << 10) + hw;
    op[0]    = acc.x * inv;
    op[1024] = acc.y * inv;
    op[2048] = acc.z * inv;
    op[3072] = acc.w * inv;
}

// ---- f32 fallback (round-5 kernel) if workspace is too small ----
__device__ __forceinline__ float dot4_group(const float4& w, const float4& V) {
    float p = w.x * V.x;
    p = fmaf(w.y, V.y, p);
    p = fmaf(w.z, V.z, p);
    p = fmaf(w.w, V.w, p);
    return group16_sum(p);
}

__global__ __launch_bounds__(256) void tweetrep_f32(
        const int* __restrict__ x, const float* __restrict__ emb,
        float* __restrict__ out)
{
    const int lane16 = threadIdx.x & 15;
    const int pix    = (blockIdx.x << 4) | (threadIdx.x >> 4);
    const int eoff   = lane16 << 2;
    const int*   xp   = x + pix * LTOK;
    const float* embl = emb + eoff;

    float4 V = make_float4(0.f, 0.f, 0.f, 0.f);
#pragma unroll
    for (int c = 0; c < 28; c += 4) {
        int4 ii = *reinterpret_cast<const int4*>(xp + c);
        float4 w0 = *reinterpret_cast<const float4*>(embl + ((size_t)ii.x << 6));
        float4 w1 = *reinterpret_cast<const float4*>(embl + ((size_t)ii.y << 6));
        float4 w2 = *reinterpret_cast<const float4*>(embl + ((size_t)ii.z << 6));
        float4 w3 = *reinterpret_cast<const float4*>(embl + ((size_t)ii.w << 6));
        V.x += (w0.x + w1.x) + (w2.x + w3.x);
        V.y += (w0.y + w1.y) + (w2.y + w3.y);
        V.z += (w0.z + w1.z) + (w2.z + w3.z);
        V.w += (w0.w + w1.w) + (w2.w + w3.w);
    }
    {
        int2 ii = *reinterpret_cast<const int2*>(xp + 28);
        float4 w0 = *reinterpret_cast<const float4*>(embl + ((size_t)ii.x << 6));
        float4 w1 = *reinterpret_cast<const float4*>(embl + ((size_t)ii.y << 6));
        V.x += w0.x + w1.x; V.y += w0.y + w1.y;
        V.z += w0.z + w1.z; V.w += w0.w + w1.w;
    }

    float4 acc = make_float4(0.f, 0.f, 0.f, 0.f);
    float  den = 0.f;
    float  m   = -3.0e38f;
#pragma unroll
    for (int c = 0; c < 28; c += 4) {
        int4 ii = *reinterpret_cast<const int4*>(xp + c);
        float4 w0 = *reinterpret_cast<const float4*>(embl + ((size_t)ii.x << 6));
        float4 w1 = *reinterpret_cast<const float4*>(embl + ((size_t)ii.y << 6));
        float4 w2 = *reinterpret_cast<const float4*>(embl + ((size_t)ii.z << 6));
        float4 w3 = *reinterpret_cast<const float4*>(embl + ((size_t)ii.w << 6));
        float p0 = dot4_group(w0, V);
        float p1 = dot4_group(w1, V);
        float p2 = dot4_group(w2, V);
        float p3 = dot4_group(w3, V);
        const float pm = fmaxf(fmaxf(p0, p1), fmaxf(p2, p3));
        const float mn = fmaxf(m, pm);
        const float sc = __builtin_exp2f((m - mn) * L2E);
        m = mn;
        const float e0 = __builtin_exp2f((p0 - mn) * L2E);
        const float e1 = __builtin_exp2f((p1 - mn) * L2E);
        const float e2 = __builtin_exp2f((p2 - mn) * L2E);
        const float e3 = __builtin_exp2f((p3 - mn) * L2E);
        acc.x *= sc; acc.y *= sc; acc.z *= sc; acc.w *= sc; den *= sc;
        acc.x = fmaf(e0, w0.x, acc.x); acc.y = fmaf(e0, w0.y, acc.y);
        acc.z = fmaf(e0, w0.z, acc.z); acc.w = fmaf(e0, w0.w, acc.w);
        acc.x = fmaf(e1, w1.x, acc.x); acc.y = fmaf(e1, w1.y, acc.y);
        acc.z = fmaf(e1, w1.z, acc.z); acc.w = fmaf(e1, w1.w, acc.w);
        acc.x = fmaf(e2, w2.x, acc.x); acc.y = fmaf(e2, w2.y, acc.y);
        acc.z = fmaf(e2, w2.z, acc.z); acc.w = fmaf(e2, w2.w, acc.w);
        acc.x = fmaf(e3, w3.x, acc.x); acc.y = fmaf(e3, w3.y, acc.y);
        acc.z = fmaf(e3, w3.z, acc.z); acc.w = fmaf(e3, w3.w, acc.w);
        den += (e0 + e1) + (e2 + e3);
    }
    {
        int2 ii = *reinterpret_cast<const int2*>(xp + 28);
        float4 w0 = *reinterpret_cast<const float4*>(embl + ((size_t)ii.x << 6));
        float4 w1 = *reinterpret_cast<const float4*>(embl + ((size_t)ii.y << 6));
        float p0 = dot4_group(w0, V);
        float p1 = dot4_group(w1, V);
        const float pm = fmaxf(p0, p1);
        const float mn = fmaxf(m, pm);
        const float sc = __builtin_exp2f((m - mn) * L2E);
        const float e0 = __builtin_exp2f((p0 - mn) * L2E);
        const float e1 = __builtin_exp2f((p1 - mn) * L2E);
        acc.x *= sc; acc.y *= sc; acc.z *= sc; acc.w *= sc; den *= sc;
        acc.x = fmaf(e0, w0.x, acc.x); acc.y = fmaf(e0, w0.y, acc.y);
        acc.z = fmaf(e0, w0.z, acc.z); acc.w = fmaf(e0, w0.w, acc.w);
        acc.x = fmaf(e1, w1.x, acc.x); acc.y = fmaf(e1, w1.y, acc.y);
        acc.z = fmaf(e1, w1.z, acc.z); acc.w = fmaf(e1, w1.w, acc.w);
        den += e0 + e1;
    }
    const float inv = __builtin_amdgcn_rcpf(den);

    const int bt = pix >> 10, hw = pix & 1023;
    float* op = out + (((size_t)(bt * 64 + eoff)) << 10) + hw;
    op[0]    = acc.x * inv;
    op[1024] = acc.y * inv;
    op[2048] = acc.z * inv;
    op[3072] = acc.w * inv;
}

extern "C" void kernel_launch(void* const* d_in, const int* in_sizes, int n_in,
                              void* d_out, int out_size, void* d_ws, size_t ws_size,
                              hipStream_t stream)
{
    const int*   x   = (const int*)d_in[0];
    const float* emb = (const float*)d_in[1];
    float*       out = (float*)d_out;

    const size_t need = (size_t)TABN * 2;   // 6.4 MB fp16 table
    if (ws_size >= need) {
        cvt_kernel<<<TABN / 4 / 256, 256, 0, stream>>>(
            (const float4*)emb, (uint2*)d_ws);
        tweetrep_f16<<<NPIX / 16, 256, 0, stream>>>(
            x, (const uint2*)d_ws, out);
    } else {
        tweetrep_f32<<<NPIX / 16, 256, 0, stream>>>(x, emb, out);
    }
}

// Round 9
// 34.920 us; speedup vs baseline: 2.4103x; 1.0926x over previous
//
#include <hip/hip_runtime.h>

// TweetRep: x (8,6,32,32,30) int32, embeddings (50000,64) f32 -> out (8,384,32,32) f32.
// Round-9: 8 pixels/wave (8-lane groups, lane = 8 dims = uint4 of fp16).
// r7->r8 halved gather traffic for only -5% => VALU-issue-bound (~34us model).
// Widening the group amortizes DPP (4->3 steps, 30->11/pixel), exp, softmax,
// rescale and addressing over 8 pixels; real FMA work unchanged. wg[30] =
// 120 VGPR held via __launch_bounds__(256,2) (budget 256) so the single
// gather survives (r2 lesson: default occupancy targets make hipcc re-gather).

#define LTOK 30
#define NPIX (8 * 6 * 32 * 32)   // 49152
#define L2E  1.4426950408889634f
#define TABROWS 50000
#define TABN (TABROWS * 64)      // 3.2M floats

typedef _Float16 h2 __attribute__((ext_vector_type(2)));

template <int CTRL>
__device__ __forceinline__ float dppadd(float v) {
    int t = __builtin_amdgcn_update_dpp(0, __float_as_int(v), CTRL, 0xF, 0xF, true);
    return v + __int_as_float(t);
}

// sum across the 8-lane group: xor1, xor2 (quad sums), then half-row mirror
// (lane i <-> 7-i within each 8-lane half) pairs the two quads.
__device__ __forceinline__ float group8_sum(float p) {
    p = dppadd<0xB1>(p);    // quad_perm {1,0,3,2}
    p = dppadd<0x4E>(p);    // quad_perm {2,3,0,1}
    p = dppadd<0x141>(p);   // row_half_mirror
    return p;
}

__device__ __forceinline__ h2 u2h(unsigned int u) {
    return __builtin_bit_cast(h2, u);
}

// ---- prep: f32 table -> fp16 table (RN) in workspace ----
__global__ __launch_bounds__(256) void cvt_kernel(
        const float4* __restrict__ in, uint2* __restrict__ out)
{
    const int i = blockIdx.x * 256 + threadIdx.x;   // 800000 threads exactly
    float4 f = in[i];
    h2 a = { (_Float16)f.x, (_Float16)f.y };
    h2 b = { (_Float16)f.z, (_Float16)f.w };
    out[i] = make_uint2(__builtin_bit_cast(unsigned int, a),
                        __builtin_bit_cast(unsigned int, b));
}

// partial dot of this lane's 8 dims against V, then 8-lane group sum
__device__ __forceinline__ float dot8(const uint4 w,
                                      const float4 Va, const float4 Vb) {
    h2 p0 = u2h(w.x), p1 = u2h(w.y), p2 = u2h(w.z), p3 = u2h(w.w);
    float p = (float)p0.x * Va.x;
    p = fmaf((float)p0.y, Va.y, p);
    p = fmaf((float)p1.x, Va.z, p);
    p = fmaf((float)p1.y, Va.w, p);
    p = fmaf((float)p2.x, Vb.x, p);
    p = fmaf((float)p2.y, Vb.y, p);
    p = fmaf((float)p3.x, Vb.z, p);
    p = fmaf((float)p3.y, Vb.w, p);
    return group8_sum(p);
}

__device__ __forceinline__ void vacc(float4& Va, float4& Vb,
                                     const uint4 w, float one) {
    h2 p0 = u2h(w.x), p1 = u2h(w.y), p2 = u2h(w.z), p3 = u2h(w.w);
    Va.x = fmaf((float)p0.x, one, Va.x); Va.y = fmaf((float)p0.y, one, Va.y);
    Va.z = fmaf((float)p1.x, one, Va.z); Va.w = fmaf((float)p1.y, one, Va.w);
    Vb.x = fmaf((float)p2.x, one, Vb.x); Vb.y = fmaf((float)p2.y, one, Vb.y);
    Vb.z = fmaf((float)p3.x, one, Vb.z); Vb.w = fmaf((float)p3.y, one, Vb.w);
}

__device__ __forceinline__ void accum(float4& Aa, float4& Ab,
                                      const uint4 w, float e) {
    h2 p0 = u2h(w.x), p1 = u2h(w.y), p2 = u2h(w.z), p3 = u2h(w.w);
    Aa.x = fmaf((float)p0.x, e, Aa.x); Aa.y = fmaf((float)p0.y, e, Aa.y);
    Aa.z = fmaf((float)p1.x, e, Aa.z); Aa.w = fmaf((float)p1.y, e, Aa.w);
    Ab.x = fmaf((float)p2.x, e, Ab.x); Ab.y = fmaf((float)p2.y, e, Ab.y);
    Ab.z = fmaf((float)p3.x, e, Ab.z); Ab.w = fmaf((float)p3.y, e, Ab.w);
}

// ---- main: single fp16 gather, 8 pixels/wave, rows live in VGPRs ----
__global__ __launch_bounds__(256, 2) void tweetrep_f16(
        const int* __restrict__ x, const uint4* __restrict__ tab,
        float* __restrict__ out)
{
    const int lane8 = threadIdx.x & 7;
    const int pix   = (blockIdx.x << 5) | (threadIdx.x >> 3);  // 32 pixels/block
    const int* xp   = x + pix * LTOK;
    // fp16 row = 64 halves = 8 uint4; this lane's 8 dims = uint4 #lane8
    const uint4* tpl = tab + lane8;

    float one = 1.0f;
    asm volatile("" : "+v"(one));   // keep fmaf((float)h, one, V) as v_fma_mix

    // ---- single gather: all 30 row-slices into registers (120 VGPR) ----
    uint4 wg[LTOK];
#pragma unroll
    for (int c = 0; c < 28; c += 4) {
        int4 ii = *reinterpret_cast<const int4*>(xp + c);
        wg[c]     = tpl[(size_t)ii.x << 3];
        wg[c + 1] = tpl[(size_t)ii.y << 3];
        wg[c + 2] = tpl[(size_t)ii.z << 3];
        wg[c + 3] = tpl[(size_t)ii.w << 3];
    }
    {
        int2 ii = *reinterpret_cast<const int2*>(xp + 28);
        wg[28] = tpl[(size_t)ii.x << 3];
        wg[29] = tpl[(size_t)ii.y << 3];
    }

    // ---- V = sum of rows (f32 accum via v_fma_mix) ----
    float4 Va = make_float4(0.f, 0.f, 0.f, 0.f);
    float4 Vb = make_float4(0.f, 0.f, 0.f, 0.f);
#pragma unroll
    for (int l = 0; l < LTOK; ++l) vacc(Va, Vb, wg[l], one);

    // ---- chunk-of-4 online softmax, consuming wg from registers ----
    float4 Aa = make_float4(0.f, 0.f, 0.f, 0.f);
    float4 Ab = make_float4(0.f, 0.f, 0.f, 0.f);
    float  den = 0.f;
    float  m   = -3.0e38f;
#pragma unroll
    for (int c = 0; c < 28; c += 4) {
        float p0 = dot8(wg[c],     Va, Vb);
        float p1 = dot8(wg[c + 1], Va, Vb);
        float p2 = dot8(wg[c + 2], Va, Vb);
        float p3 = dot8(wg[c + 3], Va, Vb);

        const float pm = fmaxf(fmaxf(p0, p1), fmaxf(p2, p3));
        const float mn = fmaxf(m, pm);
        const float sc = __builtin_exp2f((m - mn) * L2E);   // 0 on first chunk
        m = mn;
        const float e0 = __builtin_exp2f((p0 - mn) * L2E);
        const float e1 = __builtin_exp2f((p1 - mn) * L2E);
        const float e2 = __builtin_exp2f((p2 - mn) * L2E);
        const float e3 = __builtin_exp2f((p3 - mn) * L2E);
        Aa.x *= sc; Aa.y *= sc; Aa.z *= sc; Aa.w *= sc;
        Ab.x *= sc; Ab.y *= sc; Ab.z *= sc; Ab.w *= sc;
        den  *= sc;
        accum(Aa, Ab, wg[c],     e0);
        accum(Aa, Ab, wg[c + 1], e1);
        accum(Aa, Ab, wg[c + 2], e2);
        accum(Aa, Ab, wg[c + 3], e3);
        den += (e0 + e1) + (e2 + e3);
    }
    {
        float p0 = dot8(wg[28], Va, Vb);
        float p1 = dot8(wg[29], Va, Vb);
        const float pm = fmaxf(p0, p1);
        const float mn = fmaxf(m, pm);
        const float sc = __builtin_exp2f((m - mn) * L2E);
        const float e0 = __builtin_exp2f((p0 - mn) * L2E);
        const float e1 = __builtin_exp2f((p1 - mn) * L2E);
        Aa.x *= sc; Aa.y *= sc; Aa.z *= sc; Aa.w *= sc;
        Ab.x *= sc; Ab.y *= sc; Ab.z *= sc; Ab.w *= sc;
        den  *= sc;
        accum(Aa, Ab, wg[28], e0);
        accum(Aa, Ab, wg[29], e1);
        den += e0 + e1;
    }
    const float inv = __builtin_amdgcn_rcpf(den);

    // ---- out[bt*64 + e][hw], e = 8*lane8 + j ----
    const int bt = pix >> 10, hw = pix & 1023;
    float* op = out + (((size_t)(bt * 64 + (lane8 << 3))) << 10) + hw;
    op[0]        = Aa.x * inv;
    op[1024]     = Aa.y * inv;
    op[2 * 1024] = Aa.z * inv;
    op[3 * 1024] = Aa.w * inv;
    op[4 * 1024] = Ab.x * inv;
    op[5 * 1024] = Ab.y * inv;
    op[6 * 1024] = Ab.z * inv;
    op[7 * 1024] = Ab.w * inv;
}

// ---- f32 fallback (round-5 kernel) if workspace is too small ----
__device__ __forceinline__ float group16_sum(float p) {
    p = dppadd<0xB1>(p);
    p = dppadd<0x4E>(p);
    p = dppadd<0x141>(p);
    p = dppadd<0x140>(p);
    return p;
}

__device__ __forceinline__ float dot4_group(const float4& w, const float4& V) {
    float p = w.x * V.x;
    p = fmaf(w.y, V.y, p);
    p = fmaf(w.z, V.z, p);
    p = fmaf(w.w, V.w, p);
    return group16_sum(p);
}

__global__ __launch_bounds__(256) void tweetrep_f32(
        const int* __restrict__ x, const float* __restrict__ emb,
        float* __restrict__ out)
{
    const int lane16 = threadIdx.x & 15;
    const int pix    = (blockIdx.x << 4) | (threadIdx.x >> 4);
    const int eoff   = lane16 << 2;
    const int*   xp   = x + pix * LTOK;
    const float* embl = emb + eoff;

    float4 V = make_float4(0.f, 0.f, 0.f, 0.f);
#pragma unroll
    for (int c = 0; c < 28; c += 4) {
        int4 ii = *reinterpret_cast<const int4*>(xp + c);
        float4 w0 = *reinterpret_cast<const float4*>(embl + ((size_t)ii.x << 6));
        float4 w1 = *reinterpret_cast<const float4*>(embl + ((size_t)ii.y << 6));
        float4 w2 = *reinterpret_cast<const float4*>(embl + ((size_t)ii.z << 6));
        float4 w3 = *reinterpret_cast<const float4*>(embl + ((size_t)ii.w << 6));
        V.x += (w0.x + w1.x) + (w2.x + w3.x);
        V.y += (w0.y + w1.y) + (w2.y + w3.y);
        V.z += (w0.z + w1.z) + (w2.z + w3.z);
        V.w += (w0.w + w1.w) + (w2.w + w3.w);
    }
    {
        int2 ii = *reinterpret_cast<const int2*>(xp + 28);
        float4 w0 = *reinterpret_cast<const float4*>(embl + ((size_t)ii.x << 6));
        float4 w1 = *reinterpret_cast<const float4*>(embl + ((size_t)ii.y << 6));
        V.x += w0.x + w1.x; V.y += w0.y + w1.y;
        V.z += w0.z + w1.z; V.w += w0.w + w1.w;
    }

    float4 acc = make_float4(0.f, 0.f, 0.f, 0.f);
    float  den = 0.f;
    float  m   = -3.0e38f;
#pragma unroll
    for (int c = 0; c < 28; c += 4) {
        int4 ii = *reinterpret_cast<const int4*>(xp + c);
        float4 w0 = *reinterpret_cast<const float4*>(embl + ((size_t)ii.x << 6));
        float4 w1 = *reinterpret_cast<const float4*>(embl + ((size_t)ii.y << 6));
        float4 w2 = *reinterpret_cast<const float4*>(embl + ((size_t)ii.z << 6));
        float4 w3 = *reinterpret_cast<const float4*>(embl + ((size_t)ii.w << 6));
        float p0 = dot4_group(w0, V);
        float p1 = dot4_group(w1, V);
        float p2 = dot4_group(w2, V);
        float p3 = dot4_group(w3, V);
        const float pm = fmaxf(fmaxf(p0, p1), fmaxf(p2, p3));
        const float mn = fmaxf(m, pm);
        const float sc = __builtin_exp2f((m - mn) * L2E);
        m = mn;
        const float e0 = __builtin_exp2f((p0 - mn) * L2E);
        const float e1 = __builtin_exp2f((p1 - mn) * L2E);
        const float e2 = __builtin_exp2f((p2 - mn) * L2E);
        const float e3 = __builtin_exp2f((p3 - mn) * L2E);
        acc.x *= sc; acc.y *= sc; acc.z *= sc; acc.w *= sc; den *= sc;
        acc.x = fmaf(e0, w0.x, acc.x); acc.y = fmaf(e0, w0.y, acc.y);
        acc.z = fmaf(e0, w0.z, acc.z); acc.w = fmaf(e0, w0.w, acc.w);
        acc.x = fmaf(e1, w1.x, acc.x); acc.y = fmaf(e1, w1.y, acc.y);
        acc.z = fmaf(e1, w1.z, acc.z); acc.w = fmaf(e1, w1.w, acc.w);
        acc.x = fmaf(e2, w2.x, acc.x); acc.y = fmaf(e2, w2.y, acc.y);
        acc.z = fmaf(e2, w2.z, acc.z); acc.w = fmaf(e2, w2.w, acc.w);
        acc.x = fmaf(e3, w3.x, acc.x); acc.y = fmaf(e3, w3.y, acc.y);
        acc.z = fmaf(e3, w3.z, acc.z); acc.w = fmaf(e3, w3.w, acc.w);
        den += (e0 + e1) + (e2 + e3);
    }
    {
        int2 ii = *reinterpret_cast<const int2*>(xp + 28);
        float4 w0 = *reinterpret_cast<const float4*>(embl + ((size_t)ii.x << 6));
        float4 w1 = *reinterpret_cast<const float4*>(embl + ((size_t)ii.y << 6));
        float p0 = dot4_group(w0, V);
        float p1 = dot4_group(w1, V);
        const float pm = fmaxf(p0, p1);
        const float mn = fmaxf(m, pm);
        const float sc = __builtin_exp2f((m - mn) * L2E);
        const float e0 = __builtin_exp2f((p0 - mn) * L2E);
        const float e1 = __builtin_exp2f((p1 - mn) * L2E);
        acc.x *= sc; acc.y *= sc; acc.z *= sc; acc.w *= sc; den *= sc;
        acc.x = fmaf(e0, w0.x, acc.x); acc.y = fmaf(e0, w0.y, acc.y);
        acc.z = fmaf(e0, w0.z, acc.z); acc.w = fmaf(e0, w0.w, acc.w);
        acc.x = fmaf(e1, w1.x, acc.x); acc.y = fmaf(e1, w1.y, acc.y);
        acc.z = fmaf(e1, w1.z, acc.z); acc.w = fmaf(e1, w1.w, acc.w);
        den += e0 + e1;
    }
    const float inv = __builtin_amdgcn_rcpf(den);

    const int bt = pix >> 10, hw = pix & 1023;
    float* op = out + (((size_t)(bt * 64 + eoff)) << 10) + hw;
    op[0]    = acc.x * inv;
    op[1024] = acc.y * inv;
    op[2048] = acc.z * inv;
    op[3072] = acc.w * inv;
}

extern "C" void kernel_launch(void* const* d_in, const int* in_sizes, int n_in,
                              void* d_out, int out_size, void* d_ws, size_t ws_size,
                              hipStream_t stream)
{
    const int*   x   = (const int*)d_in[0];
    const float* emb = (const float*)d_in[1];
    float*       out = (float*)d_out;

    const size_t need = (size_t)TABN * 2;   // 6.4 MB fp16 table
    if (ws_size >= need) {
        cvt_kernel<<<TABN / 4 / 256, 256, 0, stream>>>(
            (const float4*)emb, (uint2*)d_ws);
        tweetrep_f16<<<NPIX / 32, 256, 0, stream>>>(
            x, (const uint4*)d_ws, out);
    } else {
        tweetrep_f32<<<NPIX / 16, 256, 0, stream>>>(x, emb, out);
    }
}